// Round 4
// baseline (639.577 us; speedup 1.0000x reference)
//
#include <hip/hip_runtime.h>

// Problem constants (from reference)
#define IN_F   4096
#define OUT_F  4096
#define RK     32      // R_MIN
#define NB1    2048    // B1
#define NB2    2048    // B2
#define LBATCH 10240   // B1 + B2*MULT
#define MAXB   2048    // worst-case rows per bucket

// ws layout (4-byte units):
//   [0..31]    cnt1 (part-1 bucket counts, by adapter w)
//   [32..63]   cnt2 (part-2 bucket counts, by group j)
//   [64..]     list1: 32 x 2048 ints (b values)
//   then       list2: 32 x 2048 ints (i values)
//   then       r: 10240 x 32 fp32 (zeroed; stage1 atomicAdds into it)

__global__ __launch_bounds__(256) void bin_rows(const int* __restrict__ wids,
                                                int* cnt1, int* cnt2,
                                                int* list1, int* list2) {
    int t = blockIdx.x * 256 + threadIdx.x;   // 0..4095
    if (t < NB1) {
        int w = wids[t];                      // 0..31
        int p = atomicAdd(&cnt1[w], 1);
        list1[w * MAXB + p] = t;
    } else {
        int i = t - NB1;                      // 0..2047
        int w4 = wids[NB1 + 4 * i];           // 32 + 4*j
        int j = (w4 - 32) >> 2;
        int p = atomicAdd(&cnt2[j], 1);
        list2[j * MAXB + p] = i;
    }
}

// Stage1 part1: r[b][c] += x[b][k0..]*A[w][k0..][c], b in bucket w.
// grid (32 w, 16 kb of 256 k). 4 waves = 4 k-slices of 64; lanes = 32 c x 2
// k-halves of 32 (combined by shfl_xor(32)). areg[32] register-stationary.
__global__ __launch_bounds__(256, 4) void s1_p1(const float* __restrict__ x,
                                                const float* __restrict__ A,
                                                const int*   __restrict__ cnt1,
                                                const int*   __restrict__ list1,
                                                float*       __restrict__ r) {
    int w    = blockIdx.x;
    int lane = threadIdx.x & 63;
    int wv   = threadIdx.x >> 6;
    int c    = lane & 31;
    int kh   = lane >> 5;
    int k0   = blockIdx.y * 256 + wv * 64 + kh * 32;

    const float* Ap = A + ((size_t)w * IN_F + k0) * RK + c;
    float areg[32];
    #pragma unroll
    for (int kk = 0; kk < 32; ++kk) areg[kk] = Ap[(size_t)kk * RK];

    __shared__ int llist[MAXB];
    int n = cnt1[w];
    for (int t = threadIdx.x; t < n; t += 256) llist[t] = list1[w * MAXB + t];
    __syncthreads();

    for (int it = 0; it < n; ++it) {
        int b = llist[it];
        const float4* x4 = (const float4*)(x + (size_t)b * IN_F + k0);
        float a0 = 0.f, a1 = 0.f, a2 = 0.f, a3 = 0.f;
        #pragma unroll
        for (int q = 0; q < 8; ++q) {
            float4 xv = x4[q];
            a0 += xv.x * areg[4 * q + 0];
            a1 += xv.y * areg[4 * q + 1];
            a2 += xv.z * areg[4 * q + 2];
            a3 += xv.w * areg[4 * q + 3];
        }
        float s = (a0 + a1) + (a2 + a3);
        s += __shfl_xor(s, 32);
        if (kh == 0) atomicAdd(&r[(size_t)b * RK + c], s);
    }
}

// Stage1 part2: rows share x across the 4 adapters of group j.
// grid (32 j, 32 kb of 128 k). Wave = adapter m; lanes = 32 c x 2 k-halves
// of 64 (shfl-combined). areg[64]; 16 float4 x-loads per row.
__global__ __launch_bounds__(256, 2) void s1_p2(const float* __restrict__ x,
                                                const float* __restrict__ A,
                                                const int*   __restrict__ cnt2,
                                                const int*   __restrict__ list2,
                                                float*       __restrict__ r) {
    int j    = blockIdx.x;
    int lane = threadIdx.x & 63;
    int m    = threadIdx.x >> 6;
    int c    = lane & 31;
    int kh   = lane >> 5;
    int a    = 32 + 4 * j + m;
    int k0   = blockIdx.y * 128 + kh * 64;

    const float* Ap = A + ((size_t)a * IN_F + k0) * RK + c;
    float areg[64];
    #pragma unroll
    for (int kk = 0; kk < 64; ++kk) areg[kk] = Ap[(size_t)kk * RK];

    __shared__ int llist[MAXB];
    int n = cnt2[j];
    for (int t = threadIdx.x; t < n; t += 256) llist[t] = list2[j * MAXB + t];
    __syncthreads();

    for (int it = 0; it < n; ++it) {
        int i = llist[it];
        const float4* x4 = (const float4*)(x + (size_t)(NB1 + i) * IN_F + k0);
        float a0 = 0.f, a1 = 0.f, a2 = 0.f, a3 = 0.f;
        #pragma unroll
        for (int q = 0; q < 16; ++q) {
            float4 xv = x4[q];
            a0 += xv.x * areg[4 * q + 0];
            a1 += xv.y * areg[4 * q + 1];
            a2 += xv.z * areg[4 * q + 2];
            a3 += xv.w * areg[4 * q + 3];
        }
        float s = (a0 + a1) + (a2 + a3);
        s += __shfl_xor(s, 32);
        if (kh == 0) atomicAdd(&r[(size_t)(NB1 + 4 * i + m) * RK + c], s);
    }
}

// Stage2 part1: out[b][o] = 2 * r[b][:] . B[w][:][o]. breg[32] stationary;
// r row read as 8 float4 broadcasts.
__global__ __launch_bounds__(256, 4) void s2_p1(const float* __restrict__ r,
                                                const float* __restrict__ B,
                                                const int*   __restrict__ cnt1,
                                                const int*   __restrict__ list1,
                                                float*       __restrict__ out) {
    int w = blockIdx.x;
    int o = blockIdx.y * 256 + threadIdx.x;

    const float* Bp = B + (size_t)w * RK * OUT_F + o;
    float breg[32];
    #pragma unroll
    for (int k = 0; k < 32; ++k) breg[k] = Bp[(size_t)k * OUT_F];

    __shared__ int llist[MAXB];
    int n = cnt1[w];
    for (int t = threadIdx.x; t < n; t += 256) llist[t] = list1[w * MAXB + t];
    __syncthreads();

    for (int it = 0; it < n; ++it) {
        int b = llist[it];
        const float4* r4 = (const float4*)(r + (size_t)b * RK);
        float a0 = 0.f, a1 = 0.f, a2 = 0.f, a3 = 0.f;
        #pragma unroll
        for (int q = 0; q < 8; ++q) {
            float4 rv = r4[q];
            a0 += rv.x * breg[4 * q + 0];
            a1 += rv.y * breg[4 * q + 1];
            a2 += rv.z * breg[4 * q + 2];
            a3 += rv.w * breg[4 * q + 3];
        }
        out[(size_t)b * OUT_F + o] = 2.f * ((a0 + a1) + (a2 + a3));
    }
}

// Stage2 part2: out[2048+i][o] = 2 * sum_m r[2048+4i+m][:] . B[32+4j+m][:][o].
// The 4 r rows are CONTIGUOUS (128 floats = 32 float4) and breg[128] is laid
// out to match linearly: breg[idx] = B[32+4j+idx/32][idx%32][o].
__global__ __launch_bounds__(256, 2) void s2_p2(const float* __restrict__ r,
                                                const float* __restrict__ B,
                                                const int*   __restrict__ cnt2,
                                                const int*   __restrict__ list2,
                                                float*       __restrict__ out) {
    int j = blockIdx.x;
    int o = blockIdx.y * 256 + threadIdx.x;

    float breg[128];
    #pragma unroll
    for (int m = 0; m < 4; ++m) {
        const float* Bp = B + (size_t)(32 + 4 * j + m) * RK * OUT_F + o;
        #pragma unroll
        for (int k = 0; k < 32; ++k) breg[m * 32 + k] = Bp[(size_t)k * OUT_F];
    }

    __shared__ int llist[MAXB];
    int n = cnt2[j];
    for (int t = threadIdx.x; t < n; t += 256) llist[t] = list2[j * MAXB + t];
    __syncthreads();

    for (int it = 0; it < n; ++it) {
        int i = llist[it];
        const float4* r4 = (const float4*)(r + (size_t)(NB1 + 4 * i) * RK);
        float a0 = 0.f, a1 = 0.f, a2 = 0.f, a3 = 0.f;
        #pragma unroll
        for (int q = 0; q < 32; ++q) {
            float4 rv = r4[q];
            a0 += rv.x * breg[4 * q + 0];
            a1 += rv.y * breg[4 * q + 1];
            a2 += rv.z * breg[4 * q + 2];
            a3 += rv.w * breg[4 * q + 3];
        }
        out[(size_t)(NB1 + i) * OUT_F + o] = 2.f * ((a0 + a1) + (a2 + a3));
    }
}

extern "C" void kernel_launch(void* const* d_in, const int* in_sizes, int n_in,
                              void* d_out, int out_size, void* d_ws, size_t ws_size,
                              hipStream_t stream) {
    const float* x    = (const float*)d_in[0];
    const int*   wids = (const int*)  d_in[2];
    const float* A    = (const float*)d_in[3];
    const float* Bm   = (const float*)d_in[4];
    float* out = (float*)d_out;

    int* wsI   = (int*)d_ws;
    int* cnt1  = wsI;
    int* cnt2  = wsI + 32;
    int* list1 = wsI + 64;
    int* list2 = list1 + 32 * MAXB;
    float* r   = (float*)(list2 + 32 * MAXB);

    hipMemsetAsync(cnt1, 0, 64 * sizeof(int), stream);
    hipMemsetAsync(r, 0, (size_t)LBATCH * RK * sizeof(float), stream);

    bin_rows<<<dim3(16), dim3(256), 0, stream>>>(wids, cnt1, cnt2, list1, list2);
    s1_p1<<<dim3(32, 16), dim3(256), 0, stream>>>(x, A, cnt1, list1, r);
    s1_p2<<<dim3(32, 32), dim3(256), 0, stream>>>(x, A, cnt2, list2, r);
    s2_p1<<<dim3(32, 16), dim3(256), 0, stream>>>(r, Bm, cnt1, list1, out);
    s2_p2<<<dim3(32, 16), dim3(256), 0, stream>>>(r, Bm, cnt2, list2, out);
}

// Round 5
// 398.035 us; speedup vs baseline: 1.6068x; 1.6068x over previous
//
#include <hip/hip_runtime.h>

// Problem constants (from reference)
#define IN_F   4096
#define OUT_F  4096
#define RK     32      // R_MIN
#define NB1    2048    // B1
#define LBATCH 10240   // B1 + B2*MULT
#define MAXB   2048    // worst-case rows per bucket
#define TILES  4       // 64-row tiles per bucket (capacity 256 rows; n~64±8)

// ws layout (ints): cnt1[32] | cnt2[32] | list1[32*2048] | list2[32*2048] | r[10240*32] f32

__global__ __launch_bounds__(256) void bin_rows(const int* __restrict__ wids,
                                                int* cnt1, int* cnt2,
                                                int* list1, int* list2) {
    int t = blockIdx.x * 256 + threadIdx.x;   // 0..4095
    if (t < NB1) {
        int w = wids[t];
        int p = atomicAdd(&cnt1[w], 1);
        list1[w * MAXB + p] = t;
    } else {
        int i = t - NB1;
        int j = (wids[NB1 + 4 * i] - 32) >> 2;
        int p = atomicAdd(&cnt2[j], 1);
        list2[j * MAXB + p] = i;
    }
}

// ---------------- Stage 1: r tile GEMM  C[64 x NC] += X[64 x 256] @ A[256 x NC]
// P2=false: bucket w, NC=32, x row = b, adapter = w, r row = b.
// P2=true : group j, NC=128 (4 adapters), x row = NB1+i, r row = NB1+4i+m.
// grid (32, 16 k-chunks of 256, TILES). 256 thr; thread = (colg 0..31, rowg 0..7),
// owns 8 rows x CPT cols. K streamed in 32-wide LDS chunks.
template<int NC, bool P2>
__global__ __launch_bounds__(256) void s1_gemm(const float* __restrict__ x,
                                               const float* __restrict__ A,
                                               const int*   __restrict__ cnt,
                                               const int*   __restrict__ list,
                                               float*       __restrict__ r) {
    constexpr int CPT = NC / 32;          // 1 or 4
    int g  = blockIdx.x;
    int tz = blockIdx.z;
    int n  = cnt[g];
    if (64 * tz >= n) return;

    int colg = threadIdx.x & 31;
    int rowg = threadIdx.x >> 5;
    int k0   = blockIdx.y * 256;

    __shared__ __align__(16) float X_lds[32][68];   // [kk][row], pad 68 -> 16B-aligned rows, fewer store conflicts
    __shared__ __align__(16) float A_lds[32][NC];   // [kk][col]
    __shared__ int rowid[64];

    if (threadIdx.x < 64) {
        int it = 64 * tz + threadIdx.x;
        rowid[threadIdx.x] = list[g * MAXB + (it < n ? it : n - 1)];
    }
    __syncthreads();

    float acc[8][CPT];
    #pragma unroll
    for (int a_ = 0; a_ < 8; ++a_)
        #pragma unroll
        for (int b_ = 0; b_ < CPT; ++b_) acc[a_][b_] = 0.f;

    for (int kc = 0; kc < 8; ++kc) {
        int kk0 = k0 + kc * 32;
        __syncthreads();
        // stage X (transposed): 64 rows x 32 k
        {
            int row = threadIdx.x >> 3;
            int k4  = (threadIdx.x & 7) * 4;
            #pragma unroll
            for (int p = 0; p < 2; ++p) {
                int rw   = row + 32 * p;
                int xrow = P2 ? (NB1 + rowid[rw]) : rowid[rw];
                float4 xv = *(const float4*)&x[(size_t)xrow * IN_F + kk0 + k4];
                X_lds[k4 + 0][rw] = xv.x;
                X_lds[k4 + 1][rw] = xv.y;
                X_lds[k4 + 2][rw] = xv.z;
                X_lds[k4 + 3][rw] = xv.w;
            }
        }
        // stage A (natural [k][col])
        if (P2) {
            #pragma unroll
            for (int p = 0; p < 4; ++p) {
                int gg  = threadIdx.x + 256 * p;       // 1024 float4
                int kkk = gg >> 5;
                int m   = (gg & 31) >> 3;
                int c4  = (gg & 7) * 4;
                float4 av = *(const float4*)&A[((size_t)(32 + 4 * g + m) * IN_F + kk0 + kkk) * RK + c4];
                *(float4*)&A_lds[kkk][m * 32 + c4] = av;
            }
        } else {
            int kkk = threadIdx.x >> 3;
            int c4  = (threadIdx.x & 7) * 4;
            float4 av = *(const float4*)&A[((size_t)g * IN_F + kk0 + kkk) * RK + c4];
            *(float4*)&A_lds[kkk][c4] = av;
        }
        __syncthreads();
        // compute 32 k
        #pragma unroll 2
        for (int kk = 0; kk < 32; ++kk) {
            float4 xa = *(const float4*)&X_lds[kk][rowg * 8];
            float4 xb = *(const float4*)&X_lds[kk][rowg * 8 + 4];
            float xv[8] = {xa.x, xa.y, xa.z, xa.w, xb.x, xb.y, xb.z, xb.w};
            float av[CPT];
            if constexpr (CPT == 4) {
                float4 a4 = *(const float4*)&A_lds[kk][colg * 4];
                av[0] = a4.x; av[1] = a4.y; av[2] = a4.z; av[3] = a4.w;
            } else {
                av[0] = A_lds[kk][colg];
            }
            #pragma unroll
            for (int rr = 0; rr < 8; ++rr)
                #pragma unroll
                for (int cc = 0; cc < CPT; ++cc)
                    acc[rr][cc] += xv[rr] * av[cc];
        }
    }
    // flush to r via atomics (k-split)
    #pragma unroll
    for (int rr = 0; rr < 8; ++rr) {
        int it = 64 * tz + rowg * 8 + rr;
        if (it < n) {
            int rid = rowid[rowg * 8 + rr];
            #pragma unroll
            for (int cc = 0; cc < CPT; ++cc) {
                int col = colg * CPT + cc;
                size_t off;
                if (P2) off = (size_t)(NB1 + 4 * rid + (col >> 5)) * RK + (col & 31);
                else    off = (size_t)rid * RK + col;
                atomicAdd(&r[off], acc[rr][cc]);
            }
        }
    }
}

// ---------------- Stage 2: Out[64 x 128] = 2 * R[64 x K] @ B[K x 128]
// P2=false: bucket w, K=32, out row = b.   P2=true: group j, K=128 (4 contiguous
// r rows, adapters 32+4j+kc), out row = NB1+i.  grid (32, 32 o-tiles, TILES).
template<bool P2>
__global__ __launch_bounds__(256) void s2_gemm(const float* __restrict__ r,
                                               const float* __restrict__ B,
                                               const int*   __restrict__ cnt,
                                               const int*   __restrict__ list,
                                               float*       __restrict__ out) {
    int g  = blockIdx.x;
    int ot = blockIdx.y;          // 128-col tile
    int tz = blockIdx.z;
    int n  = cnt[g];
    if (64 * tz >= n) return;

    int colg = threadIdx.x & 31;
    int rowg = threadIdx.x >> 5;

    __shared__ __align__(16) float R_lds[32][68];
    __shared__ __align__(16) float B_lds[32][128];
    __shared__ int rowid[64];

    if (threadIdx.x < 64) {
        int it = 64 * tz + threadIdx.x;
        rowid[threadIdx.x] = list[g * MAXB + (it < n ? it : n - 1)];
    }
    __syncthreads();

    float acc[8][4];
    #pragma unroll
    for (int a_ = 0; a_ < 8; ++a_)
        #pragma unroll
        for (int b_ = 0; b_ < 4; ++b_) acc[a_][b_] = 0.f;

    constexpr int CH = P2 ? 4 : 1;
    for (int kc = 0; kc < CH; ++kc) {
        __syncthreads();
        // stage R chunk (transposed)
        {
            int row = threadIdx.x >> 3;
            int k4  = (threadIdx.x & 7) * 4;
            #pragma unroll
            for (int p = 0; p < 2; ++p) {
                int rw  = row + 32 * p;
                int rid = rowid[rw];
                size_t roff = P2 ? ((size_t)(NB1 + 4 * rid) * RK + kc * 32 + k4)
                                 : ((size_t)rid * RK + k4);
                float4 rv = *(const float4*)&r[roff];
                R_lds[k4 + 0][rw] = rv.x;
                R_lds[k4 + 1][rw] = rv.y;
                R_lds[k4 + 2][rw] = rv.z;
                R_lds[k4 + 3][rw] = rv.w;
            }
        }
        // stage B chunk: B_lds[kk][oc] = B[a][kk][ot*128+oc]
        {
            int a = P2 ? (32 + 4 * g + kc) : g;
            #pragma unroll
            for (int p = 0; p < 4; ++p) {
                int gg  = threadIdx.x + 256 * p;     // 1024 float4
                int kkk = gg >> 5;
                int oc4 = (gg & 31) * 4;
                float4 bv = *(const float4*)&B[((size_t)a * RK + kkk) * OUT_F + ot * 128 + oc4];
                *(float4*)&B_lds[kkk][oc4] = bv;
            }
        }
        __syncthreads();
        #pragma unroll 2
        for (int kk = 0; kk < 32; ++kk) {
            float4 ra = *(const float4*)&R_lds[kk][rowg * 8];
            float4 rb = *(const float4*)&R_lds[kk][rowg * 8 + 4];
            float rv[8] = {ra.x, ra.y, ra.z, ra.w, rb.x, rb.y, rb.z, rb.w};
            float4 b4 = *(const float4*)&B_lds[kk][colg * 4];
            float bv[4] = {b4.x, b4.y, b4.z, b4.w};
            #pragma unroll
            for (int rr = 0; rr < 8; ++rr)
                #pragma unroll
                for (int cc = 0; cc < 4; ++cc)
                    acc[rr][cc] += rv[rr] * bv[cc];
        }
    }
    // store (each out element written by exactly one block)
    #pragma unroll
    for (int rr = 0; rr < 8; ++rr) {
        int it = 64 * tz + rowg * 8 + rr;
        if (it < n) {
            int rid  = rowid[rowg * 8 + rr];
            int orow = P2 ? (NB1 + rid) : rid;
            float4 o;
            o.x = 2.f * acc[rr][0]; o.y = 2.f * acc[rr][1];
            o.z = 2.f * acc[rr][2]; o.w = 2.f * acc[rr][3];
            *(float4*)&out[(size_t)orow * OUT_F + ot * 128 + colg * 4] = o;
        }
    }
}

extern "C" void kernel_launch(void* const* d_in, const int* in_sizes, int n_in,
                              void* d_out, int out_size, void* d_ws, size_t ws_size,
                              hipStream_t stream) {
    const float* x    = (const float*)d_in[0];
    const int*   wids = (const int*)  d_in[2];
    const float* A    = (const float*)d_in[3];
    const float* Bm   = (const float*)d_in[4];
    float* out = (float*)d_out;

    int* wsI   = (int*)d_ws;
    int* cnt1  = wsI;
    int* cnt2  = wsI + 32;
    int* list1 = wsI + 64;
    int* list2 = list1 + 32 * MAXB;
    float* r   = (float*)(list2 + 32 * MAXB);

    hipMemsetAsync(cnt1, 0, 64 * sizeof(int), stream);
    hipMemsetAsync(r, 0, (size_t)LBATCH * RK * sizeof(float), stream);

    bin_rows<<<dim3(16), dim3(256), 0, stream>>>(wids, cnt1, cnt2, list1, list2);
    s1_gemm<32, false><<<dim3(32, 16, TILES), dim3(256), 0, stream>>>(x, A, cnt1, list1, r);
    s1_gemm<128, true><<<dim3(32, 16, TILES), dim3(256), 0, stream>>>(x, A, cnt2, list2, r);
    s2_gemm<false><<<dim3(32, 32, TILES), dim3(256), 0, stream>>>(r, Bm, cnt1, list1, out);
    s2_gemm<true ><<<dim3(32, 32, TILES), dim3(256), 0, stream>>>(r, Bm, cnt2, list2, out);
}